// Round 10
// baseline (457.424 us; speedup 1.0000x reference)
//
#include <hip/hip_runtime.h>
#include <hip/hip_bf16.h>

#define N_NODES 50000
#define T_STEPS 8
#define CIN     32
#define HDIM    128
#define E_EDGES 800000
#define NBLK    196          // ceil(N_NODES/256)

// LDS layout (shorts): A [12 ks][4 ri][64 slot][8]
//   ks 0-3  : sp            ks 4-7 : h buf0        ks 8-11: h buf1
// A_s @24576 shorts (8KB); c1f (f32) @28672 shorts (16KB). Total 72KB.
#define AS_BASE 24576
#define C1_BASE 28672

typedef __attribute__((ext_vector_type(8))) short  short8;
typedef __attribute__((ext_vector_type(4))) float  f32x4;

template<int N> struct ic { static constexpr int v = N; };

__device__ __forceinline__ ushort f2b(float f) {
    __hip_bfloat16 b = __float2bfloat16(f);
    return *reinterpret_cast<ushort*>(&b);
}
__device__ __forceinline__ float b2f(ushort u) { return __uint_as_float(((uint)u) << 16); }
__device__ __forceinline__ float sigm(float x)  { return 1.f / (1.f + __expf(-x)); }
__device__ __forceinline__ float tanhx(float x) { float e = __expf(2.f * x); return 1.f - 2.f / (e + 1.f); }
// fragment-slot swizzle: spreads simultaneous epilogue writes across bank slots
__device__ __forceinline__ int SW(int fl) { return fl ^ (fl >> 3); }

// ---------------------------------------------------------------- CSR build
__global__ void k_deg(const int* __restrict__ ei, int* __restrict__ deg) {
    int e = blockIdx.x * 256 + threadIdx.x;
    if (e < E_EDGES) atomicAdd(&deg[ei[E_EDGES + e]], 1);
}

__global__ __launch_bounds__(256)
void k_scan1(const int* __restrict__ deg, int* __restrict__ incl, int* __restrict__ bsum) {
    __shared__ int sA[256], sB[256];
    int tid = threadIdx.x;
    int i = blockIdx.x * 256 + tid;
    sA[tid] = (i < N_NODES) ? deg[i] : 0;
    __syncthreads();
    int* rd = sA; int* wr = sB;
    for (int off = 1; off < 256; off <<= 1) {
        int v = rd[tid];
        if (tid >= off) v += rd[tid - off];
        wr[tid] = v;
        __syncthreads();
        int* tmp = rd; rd = wr; wr = tmp;
    }
    incl[i] = rd[tid];
    if (tid == 255) bsum[blockIdx.x] = rd[255];
}

__global__ void k_scan2(const int* __restrict__ bsum, int* __restrict__ boff,
                        int* __restrict__ row_ptr) {
    __shared__ int sA[256], sB[256];
    int tid = threadIdx.x;
    int v0 = (tid < NBLK) ? bsum[tid] : 0;
    sA[tid] = v0;
    __syncthreads();
    int* rd = sA; int* wr = sB;
    for (int off = 1; off < 256; off <<= 1) {
        int v = rd[tid];
        if (tid >= off) v += rd[tid - off];
        wr[tid] = v;
        __syncthreads();
        int* tmp = rd; rd = wr; wr = tmp;
    }
    if (tid < NBLK) boff[tid] = rd[tid] - v0;
    if (tid == NBLK - 1) row_ptr[N_NODES] = rd[tid];
}

__global__ __launch_bounds__(256)
void k_scan3(const int* __restrict__ deg, const int* __restrict__ incl,
             const int* __restrict__ boff, int* __restrict__ row_ptr,
             int* __restrict__ cursor, float* __restrict__ rdeg) {
    int i = blockIdx.x * 256 + threadIdx.x;
    if (i >= N_NODES) return;
    int d = deg[i];
    int excl = incl[i] - d + boff[blockIdx.x];
    row_ptr[i] = excl;
    cursor[i]  = excl;
    rdeg[i] = 1.0f / (float)max(d, 1);
}

__global__ void k_bucket(const int* __restrict__ ei, int* __restrict__ cursor,
                         int* __restrict__ csr_src) {
    int e = blockIdx.x * 256 + threadIdx.x;
    if (e < E_EDGES) {
        int d = ei[E_EDGES + e];
        int slot = atomicAdd(&cursor[d], 1);
        csr_src[slot] = ei[e];
    }
}

// ---------------------------------------------------------------- x -> bf16
__global__ __launch_bounds__(256)
void k_xbf(const float* __restrict__ x, ushort* __restrict__ xb) {
    size_t i = ((size_t)blockIdx.x * 256 + threadIdx.x) * 4;
    float4 v = *(const float4*)(x + i);
    ushort4 o; o.x = f2b(v.x); o.y = f2b(v.y); o.z = f2b(v.z); o.w = f2b(v.w);
    *(ushort4*)(xb + i) = o;
}

// ------------------------------------------------- fragment-order B packing
// Bf: rz [16 ct][8 ks][64][8];  n1 @65536: [8 ct][4 ks][64][8];
//     n2 @81920: [8 ct][4 ks][64][8];  Bsf: [8 ct][2 ks][64][8];
//     B2f: [6 ct][4 ks][64][8]
__global__ void k_pack(const float* __restrict__ Wih, const float* __restrict__ Whh,
                       const float* __restrict__ Wl,  const float* __restrict__ Wr,
                       const float* __restrict__ Wrec,const float* __restrict__ Wc1,
                       short* __restrict__ Bf, short* __restrict__ Bsf, short* __restrict__ B2f) {
    int i = blockIdx.x * 256 + threadIdx.x;
    if (i < 65536) {                                   // rz
        int b = i & 7, lane = (i >> 3) & 63, ks = (i >> 9) & 7, ct = i >> 12;
        int col = ct * 16 + (lane & 15);
        int k = ks * 32 + ((lane >> 4) << 3) + b;
        float v = (k < 128) ? Wih[col * 128 + k] : Whh[col * 128 + (k - 128)];
        Bf[i] = (short)f2b(v);
    } else if (i < 81920) {                            // n1
        int t2 = i - 65536;
        int b = t2 & 7, lane = (t2 >> 3) & 63, ks = (t2 >> 9) & 3, ct = t2 >> 11;
        int col = 256 + ct * 16 + (lane & 15);
        int k = ks * 32 + ((lane >> 4) << 3) + b;
        Bf[i] = (short)f2b(Wih[col * 128 + k]);
    } else if (i < 98304) {                            // n2
        int t2 = i - 81920;
        int b = t2 & 7, lane = (t2 >> 3) & 63, ks = (t2 >> 9) & 3, ct = t2 >> 11;
        int col = 256 + ct * 16 + (lane & 15);
        int k = ks * 32 + ((lane >> 4) << 3) + b;
        Bf[i] = (short)f2b(Whh[col * 128 + k]);
    } else if (i < 106496) {                           // Bsf
        int t2 = i - 98304;
        int b = t2 & 7, lane = (t2 >> 3) & 63, ks = (t2 >> 9) & 1, ct = t2 >> 10;
        int col = ct * 16 + (lane & 15);
        int k = ks * 32 + ((lane >> 4) << 3) + b;
        float v = (k < 32) ? Wl[col * 32 + k] : Wr[col * 32 + (k - 32)];
        Bsf[t2] = (short)f2b(v);
    } else if (i < 118784) {                           // B2f
        int t3 = i - 106496;
        int b = t3 & 7, lane = (t3 >> 3) & 63, ks = (t3 >> 9) & 3, ct = t3 >> 11;
        int col = ct * 16 + (lane & 15);
        int k = ks * 32 + ((lane >> 4) << 3) + b;
        float v = (col < 32) ? Wrec[col * 128 + k] : Wc1[(col - 32) * 128 + k];
        B2f[t3] = (short)f2b(v);
    }
}

// ---------------- mean aggregation over bf16 x, all timesteps, f32 accum
__global__ __launch_bounds__(256)
void k_agg_all(const ushort* __restrict__ xb, const int* __restrict__ row_ptr,
               const int* __restrict__ csr_src, const float* __restrict__ rdeg,
               ushort* __restrict__ aggb) {
    int g = blockIdx.x * 256 + threadIdx.x;
    int node = g >> 3, st = (g & 7) * 4;
    if (node >= N_NODES) return;
    int e0 = row_ptr[node], e1 = row_ptr[node + 1];
    float acc[8][4];
#pragma unroll
    for (int t = 0; t < 8; ++t)
#pragma unroll
        for (int c = 0; c < 4; ++c) acc[t][c] = 0.f;
    for (int e = e0; e < e1; ++e) {
        int s = csr_src[e];
        const ushort* b = xb + (size_t)s * (T_STEPS * CIN) + st;
#pragma unroll
        for (int t = 0; t < 8; ++t) {
            ushort4 v = *(const ushort4*)(b + t * CIN);
            acc[t][0] += b2f(v.x); acc[t][1] += b2f(v.y);
            acc[t][2] += b2f(v.z); acc[t][3] += b2f(v.w);
        }
    }
    float r = rdeg[node];
    ushort* o = aggb + (size_t)node * (T_STEPS * CIN) + st;
#pragma unroll
    for (int t = 0; t < 8; ++t) {
        ushort4 v; v.x = f2b(acc[t][0] * r); v.y = f2b(acc[t][1] * r);
        v.z = f2b(acc[t][2] * r); v.w = f2b(acc[t][3] * r);
        *(ushort4*)(o + t * CIN) = v;
    }
}

// GRU row-half: rows RH*32..+31; HB = compile-time ks base of the h buffer
// (acc regs halved + static LDS offsets -> minimal liveness & address VALU)
template<int RH, int HB>
__device__ __forceinline__ void gru_half(const short* lds, const short* __restrict__ Bf,
                                         int swl, int wv, int lane,
                                         float br_, float bz_,
                                         float bihn, float bhhn, float (&hold)[4][4]) {
    f32x4 accR[2], accZ[2], accN1[2], accN2[2];
#pragma unroll
    for (int ri = 0; ri < 2; ++ri) {
        accR[ri]  = (f32x4){0.f, 0.f, 0.f, 0.f};
        accZ[ri]  = (f32x4){0.f, 0.f, 0.f, 0.f};
        accN1[ri] = (f32x4){0.f, 0.f, 0.f, 0.f};
        accN2[ri] = (f32x4){0.f, 0.f, 0.f, 0.f};
    }
#pragma unroll
    for (int ks = 0; ks < 4; ++ks) {               // sp half (k<128), A ks0..3
        short8 av[2];
#pragma unroll
        for (int ri = 0; ri < 2; ++ri)
            av[ri] = *(const short8*)&lds[((ks * 4 + RH * 2 + ri) * 64 + swl) * 8];
        short8 b0 = *(const short8*)(Bf + (((0 * 8 + wv) * 8 + ks) * 64 + lane) * 8);
        short8 b1 = *(const short8*)(Bf + (((1 * 8 + wv) * 8 + ks) * 64 + lane) * 8);
        short8 bn = *(const short8*)(Bf + (65536 + ((wv * 4 + ks) * 64 + lane) * 8));
#pragma unroll
        for (int ri = 0; ri < 2; ++ri) {
            accR[ri]  = __builtin_amdgcn_mfma_f32_16x16x32_bf16(av[ri], b0, accR[ri], 0, 0, 0);
            accZ[ri]  = __builtin_amdgcn_mfma_f32_16x16x32_bf16(av[ri], b1, accZ[ri], 0, 0, 0);
            accN1[ri] = __builtin_amdgcn_mfma_f32_16x16x32_bf16(av[ri], bn, accN1[ri], 0, 0, 0);
        }
    }
#pragma unroll
    for (int kk = 0; kk < 4; ++kk) {               // h half (k>=128), A HB..HB+3
        int ks = 4 + kk;
        short8 av[2];
#pragma unroll
        for (int ri = 0; ri < 2; ++ri)
            av[ri] = *(const short8*)&lds[(((HB + kk) * 4 + RH * 2 + ri) * 64 + swl) * 8];
        short8 b0 = *(const short8*)(Bf + (((0 * 8 + wv) * 8 + ks) * 64 + lane) * 8);
        short8 b1 = *(const short8*)(Bf + (((1 * 8 + wv) * 8 + ks) * 64 + lane) * 8);
        short8 bn = *(const short8*)(Bf + (81920 + ((wv * 4 + kk) * 64 + lane) * 8));
#pragma unroll
        for (int ri = 0; ri < 2; ++ri) {
            accR[ri]  = __builtin_amdgcn_mfma_f32_16x16x32_bf16(av[ri], b0, accR[ri], 0, 0, 0);
            accZ[ri]  = __builtin_amdgcn_mfma_f32_16x16x32_bf16(av[ri], b1, accZ[ri], 0, 0, 0);
            accN2[ri] = __builtin_amdgcn_mfma_f32_16x16x32_bf16(av[ri], bn, accN2[ri], 0, 0, 0);
        }
    }
#pragma unroll
    for (int ri = 0; ri < 2; ++ri)
#pragma unroll
        for (int q = 0; q < 4; ++q) {
            float r = sigm(accR[ri][q] + br_);
            float z = sigm(accZ[ri][q] + bz_);
            float nn = tanhx(accN1[ri][q] + bihn + r * (accN2[ri][q] + bhhn));
            hold[RH * 2 + ri][q] = (1.f - z) * nn + z * hold[RH * 2 + ri][q];
        }
}

// --------- ALL 8 timesteps fused, 2 barriers/step, h double-buffered in LDS.
// t-loop unrolled x2 so both h-buffer bases are COMPILE-TIME (ds offsets =
// immediates, no runtime base rematerialization). P1 runs heads(t-1) BEFORE
// SAGE(t) with sched_barrier between: accH dies before accS is born ->
// P1 register peak halves (R7-R9 kept ~60-68MB/dispatch scratch from P1
// liveness at the 128-VGPR target).
__global__ __launch_bounds__(512, 2)
void k_rec(const ushort* __restrict__ aggb, const ushort* __restrict__ xb,
           const short* __restrict__ Bsf, const short* __restrict__ Bf,
           const short* __restrict__ B2f,
           const float* __restrict__ bl,
           const float* __restrict__ b_ih, const float* __restrict__ b_hh,
           const float* __restrict__ b_rec, const float* __restrict__ b_c1,
           const float* __restrict__ W_c2, const float* __restrict__ b_c2,
           float* __restrict__ out_rec, float* __restrict__ out_cls) {
    extern __shared__ short lds[];
    float* const c1f = (float*)&lds[C1_BASE];
    const int tid = threadIdx.x;
    const int nb  = blockIdx.x * 64;
    const int wv   = __builtin_amdgcn_readfirstlane(tid >> 6);
    const int lane = tid & 63;
    const int li   = lane & 15, lq = lane >> 4;
    const int j    = wv * 16 + li;
    const int swl  = SW(lane);

    // zero h buffer 0 (A ks4..7) -- read buffer for t=0
    for (int c = tid; c < 1024; c += 512)
        *(short8*)&lds[8192 + c * 8] = (short8){0, 0, 0, 0, 0, 0, 0, 0};

    float hold[4][4];
#pragma unroll
    for (int ri = 0; ri < 4; ++ri)
#pragma unroll
        for (int q = 0; q < 4; ++q) hold[ri][q] = 0.f;

    // hoisted per-lane biases
    const float blc  = bl[j];
    const float br_  = b_ih[j]       + b_hh[j];
    const float bz_  = b_ih[128 + j] + b_hh[128 + j];
    const float bihn = b_ih[256 + j], bhhn = b_hh[256 + j];
    float bhead = 0.f;
    if (wv < 2)      bhead = b_rec[j];
    else if (wv < 6) bhead = b_c1[j - 32];

    // staging geometry + prefetch (t=0 in prologue)
    const int snode = tid >> 3, sk0 = (tid & 7) * 8;
    const int sgn = nb + snode;
    const ushort* sp0 = nullptr;
    if (sgn < N_NODES)
        sp0 = ((sk0 < 32) ? aggb : xb) + (size_t)sgn * (T_STEPS * CIN) + (sk0 & 31);
    const int sdst = AS_BASE + (((sk0 >> 5) * 4 + (snode >> 4)) * 64
                                + SW(((sk0 & 31) >> 3) * 16 + (snode & 15))) * 8;
    short8 pv = (short8){0, 0, 0, 0, 0, 0, 0, 0};
    if (sp0) pv = *(const short8*)(sp0);

    // heads GEMM on h in buffer HB (compile-time); writes out_rec(tt) / c1f
    auto do_heads = [&](auto hbc, int tt) {
        constexpr int hbase = decltype(hbc)::v;
        f32x4 accH[4];
#pragma unroll
        for (int ri = 0; ri < 4; ++ri) accH[ri] = (f32x4){0.f, 0.f, 0.f, 0.f};
#pragma unroll
        for (int ksh = 0; ksh < 4; ++ksh) {
            short8 a[4];
#pragma unroll
            for (int ri = 0; ri < 4; ++ri)
                a[ri] = *(short8*)&lds[(((hbase + ksh) * 4 + ri) * 64 + swl) * 8];
            short8 b = *(const short8*)(B2f + ((wv * 4 + ksh) * 64 + lane) * 8);
#pragma unroll
            for (int ri = 0; ri < 4; ++ri)
                accH[ri] = __builtin_amdgcn_mfma_f32_16x16x32_bf16(a[ri], b, accH[ri], 0, 0, 0);
        }
        if (wv < 2) {
#pragma unroll
            for (int ri = 0; ri < 4; ++ri)
#pragma unroll
                for (int q = 0; q < 4; ++q) {
                    int row = ri * 16 + lq * 4 + q, gn = nb + row;
                    if (gn < N_NODES)
                        out_rec[(size_t)gn * (T_STEPS * 32) + tt * 32 + j] = accH[ri][q] + bhead;
                }
        } else {
            int cc = j - 32;
#pragma unroll
            for (int ri = 0; ri < 4; ++ri)
#pragma unroll
                for (int q = 0; q < 4; ++q) {
                    int row = ri * 16 + lq * 4 + q;
                    c1f[row * 64 + (cc ^ (row & 31))] = fmaxf(accH[ri][q] + bhead, 0.f);
                }
        }
    };
    // SAGE GEMM + relu + sp write (A ks0..3)
    auto do_sage = [&]() {
        f32x4 accS[4];
#pragma unroll
        for (int ri = 0; ri < 4; ++ri) accS[ri] = (f32x4){0.f, 0.f, 0.f, 0.f};
#pragma unroll
        for (int ks = 0; ks < 2; ++ks) {
            short8 a[4];
#pragma unroll
            for (int ri = 0; ri < 4; ++ri)
                a[ri] = *(short8*)&lds[AS_BASE + ((ks * 4 + ri) * 64 + swl) * 8];
            short8 b = *(const short8*)(Bsf + ((wv * 2 + ks) * 64 + lane) * 8);
#pragma unroll
            for (int ri = 0; ri < 4; ++ri)
                accS[ri] = __builtin_amdgcn_mfma_f32_16x16x32_bf16(a[ri], b, accS[ri], 0, 0, 0);
        }
        int ks_t = j >> 5, lh = (j & 31) >> 3, jj = j & 7;
#pragma unroll
        for (int ri = 0; ri < 4; ++ri)
#pragma unroll
            for (int q = 0; q < 4; ++q) {
                float v = fmaxf(accS[ri][q] + blc, 0.f);
                lds[((ks_t * 4 + ri) * 64 + SW(lh * 16 + lq * 4 + q)) * 8 + jj] = (short)f2b(v);
            }
    };
    auto do_cls = [&](int tt) {
        int node = tid >> 3, st = tid & 7, gn2 = nb + node;
        float s = 0.f;
#pragma unroll
        for (int c = 0; c < 8; ++c) {
            int q = st * 8 + c;
            s = fmaf(W_c2[q], c1f[node * 64 + (q ^ (node & 31))], s);
        }
        s += __shfl_xor(s, 1);
        s += __shfl_xor(s, 2);
        s += __shfl_xor(s, 4);
        if (st == 0 && gn2 < N_NODES)
            out_cls[(size_t)gn2 * T_STEPS + tt] = sigm(s + b_c2[0]);
    };
    auto hwrite = [&](auto hbc) {
        constexpr int hbw = decltype(hbc)::v;
        int ks_h = hbw + (j >> 5), lh_h = (j & 31) >> 3, jj_h = j & 7;
#pragma unroll
        for (int ri = 0; ri < 4; ++ri)
#pragma unroll
            for (int q = 0; q < 4; ++q)
                lds[((ks_h * 4 + ri) * 64 + SW(lh_h * 16 + lq * 4 + q)) * 8 + jj_h]
                    = (short)f2b(hold[ri][q]);
    };

#pragma unroll 1
    for (int th = 0; th < T_STEPS; th += 2) {
        // ================= even step: t = th, h read @ks4, write @ks8 ======
        {
            const int t = th;
            *(short8*)&lds[sdst] = pv;
            __syncthreads();                           // B1
            if (sp0 && t + 1 < T_STEPS) pv = *(const short8*)(sp0 + (t + 1) * CIN);
            if (t > 0 && wv < 6) do_heads(ic<4>{}, t - 1);
            __builtin_amdgcn_sched_barrier(0);         // accH dead before accS born
            do_sage();
            __syncthreads();                           // B2
            gru_half<0, 4>(lds, Bf, swl, wv, lane, br_, bz_, bihn, bhhn, hold);
            __builtin_amdgcn_sched_barrier(0);
            gru_half<1, 4>(lds, Bf, swl, wv, lane, br_, bz_, bihn, bhhn, hold);
            if (t > 0) do_cls(t - 1);
            hwrite(ic<8>{});                           // h(t) -> buf1
        }
        // ================= odd step: t = th+1, h read @ks8, write @ks4 =====
        {
            const int t = th + 1;
            *(short8*)&lds[sdst] = pv;
            __syncthreads();                           // B1
            if (sp0 && t + 1 < T_STEPS) pv = *(const short8*)(sp0 + (t + 1) * CIN);
            if (wv < 6) do_heads(ic<8>{}, t - 1);
            __builtin_amdgcn_sched_barrier(0);
            do_sage();
            __syncthreads();                           // B2
            gru_half<0, 8>(lds, Bf, swl, wv, lane, br_, bz_, bihn, bhhn, hold);
            __builtin_amdgcn_sched_barrier(0);
            gru_half<1, 8>(lds, Bf, swl, wv, lane, br_, bz_, bihn, bhhn, hold);
            do_cls(t - 1);
            hwrite(ic<4>{});                           // h(t) -> buf0
        }
    }

    // ---- epilogue: heads + cls for t = 7 (h(7) in buf0 = ks4) ----
    __syncthreads();
    if (wv < 6) do_heads(ic<4>{}, T_STEPS - 1);
    __syncthreads();
    do_cls(T_STEPS - 1);
}

// ---------------------------------------------------------------- launcher
extern "C" void kernel_launch(void* const* d_in, const int* in_sizes, int n_in,
                              void* d_out, int out_size, void* d_ws, size_t ws_size,
                              hipStream_t stream) {
    const float* x     = (const float*)d_in[0];
    const int*   ei    = (const int*)  d_in[1];
    const float* Wl    = (const float*)d_in[2];
    const float* bl    = (const float*)d_in[3];
    const float* Wr    = (const float*)d_in[4];
    const float* W_ih  = (const float*)d_in[5];
    const float* b_ih  = (const float*)d_in[6];
    const float* W_hh  = (const float*)d_in[7];
    const float* b_hh  = (const float*)d_in[8];
    const float* W_rec = (const float*)d_in[9];
    const float* b_rec = (const float*)d_in[10];
    const float* W_c1  = (const float*)d_in[11];
    const float* b_c1  = (const float*)d_in[12];
    const float* W_c2  = (const float*)d_in[13];
    const float* b_c2  = (const float*)d_in[14];

    char* wp = (char*)d_ws;
    auto alloc = [&](size_t bytes) -> char* {
        char* p = wp; wp += (bytes + 255) & ~(size_t)255; return p;
    };
    int*    deg     = (int*)   alloc((size_t)N_NODES * 4);
    int*    row_ptr = (int*)   alloc((size_t)(N_NODES + 1) * 4);
    int*    cursor  = (int*)   alloc((size_t)N_NODES * 4);
    int*    csr_src = (int*)   alloc((size_t)E_EDGES * 4);
    float*  rdeg    = (float*) alloc((size_t)N_NODES * 4);
    int*    incl    = (int*)   alloc((size_t)NBLK * 256 * 4);
    int*    bsum    = (int*)   alloc((size_t)256 * 4);
    int*    boff    = (int*)   alloc((size_t)256 * 4);
    short*  Bf      = (short*) alloc((size_t)98304 * 2);
    short*  Bsf     = (short*) alloc((size_t)8192 * 2);
    short*  B2f     = (short*) alloc((size_t)12288 * 2);
    ushort* xb      = (ushort*)alloc((size_t)N_NODES * T_STEPS * CIN * 2);
    ushort* aggb    = (ushort*)alloc((size_t)N_NODES * T_STEPS * CIN * 2);

    float* out_rec = (float*)d_out;
    float* out_cls = out_rec + (size_t)N_NODES * T_STEPS * 32;

    hipMemsetAsync(deg, 0, (size_t)N_NODES * 4, stream);

    k_deg   <<<(E_EDGES + 255) / 256, 256, 0, stream>>>(ei, deg);
    k_scan1 <<<NBLK, 256, 0, stream>>>(deg, incl, bsum);
    k_scan2 <<<1, 256, 0, stream>>>(bsum, boff, row_ptr);
    k_scan3 <<<NBLK, 256, 0, stream>>>(deg, incl, boff, row_ptr, cursor, rdeg);
    k_bucket<<<(E_EDGES + 255) / 256, 256, 0, stream>>>(ei, cursor, csr_src);
    k_xbf   <<<12500, 256, 0, stream>>>(x, xb);
    k_pack  <<<464, 256, 0, stream>>>(W_ih, W_hh, Wl, Wr, W_rec, W_c1, Bf, Bsf, B2f);

    k_agg_all<<<(N_NODES * 8 + 255) / 256, 256, 0, stream>>>(
        xb, row_ptr, csr_src, rdeg, aggb);

    const int kRecLds = 73728;    // 72KB dynamic -> 2 blocks/CU (144 <= 160KB)
    hipFuncSetAttribute((const void*)k_rec,
                        hipFuncAttributeMaxDynamicSharedMemorySize, kRecLds);
    k_rec<<<(N_NODES + 63) / 64, 512, kRecLds, stream>>>(
        aggb, xb, Bsf, Bf, B2f, bl, b_ih, b_hh, b_rec, b_c1, W_c2, b_c2,
        out_rec, out_cls);
}